// Round 7
// baseline (1129.799 us; speedup 1.0000x reference)
//
#include <hip/hip_runtime.h>
#include <hip/hip_bf16.h>

// ---- problem constants ----
#define SEM_DIM   256
#define CODEBOOK  8192
#define B_        8
#define T_        4096
#define D_        292
#define NCH       37
#define EPSV      1e-5f
#define NS        2
#define DELTA     0.03f
#define CAPMAX    24
#define CAPFALL   11

typedef unsigned short u16;
typedef unsigned long long u64;
typedef float v4f __attribute__((ext_vector_type(4)));
typedef short v8s __attribute__((ext_vector_type(8)));

template<int S> struct IC { static constexpr int v = S; };

constexpr int ROWS = B_ * T_;                 // 32768
// d_out used as flat scratch until the final writers run (aliasing order
// audited: all scratch dead before overwrite; full output coverage per call).
constexpr size_t OFF_XH   = 0;                // u16[32768*256] = 4,194,304 fl
constexpr size_t OFF_XL   = 4194304;
constexpr size_t OFF_EH   = 8388608;          // u16[8192*256] = 1,048,576 fl
constexpr size_t OFF_EL   = 9437184;
constexpr size_t OFF_E2   = 10485760;         // f32[8192] -> 10,493,952
constexpr size_t OFF_AMIN = 10493952;         // u64[32768] -> 10,559,488
constexpr size_t OFF_CNT  = 10559488;         // i32[32768] -> 10,592,256
constexpr size_t OFF_CAND = 10592256;         // u16[32768*11] -> 10,772,480
constexpr size_t RECON_OFF = 1212416;

__device__ __forceinline__ u16 bf16bits(float v) {
    __hip_bfloat16 h = __float2bfloat16(v);
    return *(u16*)&h;
}
__device__ __forceinline__ float bf16val(u16 b) {
    __hip_bfloat16 h; *(u16*)&h = b; return __bfloat162float(h);
}
__device__ __forceinline__ unsigned enc_f(float f) {
    unsigned u = __float_as_uint(f);
    return (u & 0x80000000u) ? ~u : (u | 0x80000000u);
}

// ---- kernel 0: init amin/cnt ----
__global__ __launch_bounds__(256) void init_kernel(u64* __restrict__ amin,
                                                   int* __restrict__ cnt)
{
    int r = blockIdx.x * 256 + threadIdx.x;
    amin[r] = 0xFFFFFFFFFFFFFFFFull;
    cnt[r] = 0;
}

// ---- kernel 1: Eh/El = split-bf16(es/max(cu,eps)); e2 = sum(emb^2) ----
__global__ __launch_bounds__(256) void prep_emb_kernel(
    const float* __restrict__ es, const float* __restrict__ cu,
    u16* __restrict__ Eh, u16* __restrict__ El, float* __restrict__ e2)
{
    int c = blockIdx.x;
    int d = threadIdx.x;
    float denom = fmaxf(cu[c], EPSV);
    float v = es[(size_t)c * SEM_DIM + d] / denom;   // IEEE div, matches ref
    u16 hb = bf16bits(v);
    float rr = v - bf16val(hb);
    Eh[(size_t)c * SEM_DIM + d] = hb;
    El[(size_t)c * SEM_DIM + d] = bf16bits(rr);

    float s = v * v;
    #pragma unroll
    for (int m = 32; m >= 1; m >>= 1) s += __shfl_xor(s, m);
    __shared__ float red[4];
    int lane = threadIdx.x & 63, w = threadIdx.x >> 6;
    if (lane == 0) red[w] = s;
    __syncthreads();
    if (threadIdx.x == 0)
        e2[c] = red[0] + red[1] + red[2] + red[3];
}

// ---- kernel 2: transpose-cast x[:, :256, :] -> Xh, Xl row-major (m,k) ----
__global__ __launch_bounds__(256) void prep_x_kernel(
    const float* __restrict__ x, u16* __restrict__ Xh, u16* __restrict__ Xl)
{
    __shared__ float tile[64][65];
    int bidx = blockIdx.x;            // 8 * 64 * 4
    int dc = bidx & 3;
    int tc = (bidx >> 2) & 63;
    int b  = bidx >> 8;
    int d0 = dc * 64, t0 = tc * 64;
    int tx = threadIdx.x & 63;
    int dq = threadIdx.x >> 6;
    #pragma unroll
    for (int i = 0; i < 16; i++) {
        int d = dq * 16 + i;
        tile[d][tx] = x[((size_t)b * D_ + d0 + d) * T_ + t0 + tx];
    }
    __syncthreads();
    #pragma unroll
    for (int j = 0; j < 2; j++) {
        int lin = threadIdx.x * 2 + j;      // 0..511
        int tr  = lin >> 3;
        int ch  = lin & 7;
        unsigned hw[4], lw[4];
        #pragma unroll
        for (int p = 0; p < 4; p++) {
            float v0 = tile[ch * 8 + p * 2 + 0][tr];
            float v1 = tile[ch * 8 + p * 2 + 1][tr];
            u16 h0 = bf16bits(v0), h1 = bf16bits(v1);
            u16 l0 = bf16bits(v0 - bf16val(h0));
            u16 l1 = bf16bits(v1 - bf16val(h1));
            hw[p] = (unsigned)h0 | ((unsigned)h1 << 16);
            lw[p] = (unsigned)l0 | ((unsigned)l1 << 16);
        }
        size_t off = ((size_t)b * T_ + t0 + tr) * SEM_DIM + d0 + ch * 8;
        *(uint4*)(Xh + off) = make_uint4(hw[0], hw[1], hw[2], hw[3]);
        *(uint4*)(Xl + off) = make_uint4(lw[0], lw[1], lw[2], lw[3]);
    }
}

// ---- kernel 3: LDS-free MFMA GEMM. A resident in VGPRs; B fragments loaded
//      global->VGPR straight from the (XCD-pinned) L2-hot panel; named
//      double-buffered B regs (compile-time parity); no barriers at all. ----
#define GBM 64
#define NTILES (CODEBOOK / NS / 64)           // 64 n-tiles of 64 codes

__global__ __launch_bounds__(256, 2) void gemm_emit_kernel(
    const u16* __restrict__ Xh, const u16* __restrict__ Xl,
    const u16* __restrict__ Eh, const u16* __restrict__ El,
    const float* __restrict__ e2,
    u64* __restrict__ amin, int* __restrict__ cnt, u16* __restrict__ cand,
    int cap)
{
    int tid  = threadIdx.x;
    int lane = tid & 63, wid = tid >> 6;
    int wm = wid >> 1, wn = wid & 1;          // 2x2 waves; wave tile 32m x 32n
    int l15 = lane & 15, l4 = lane >> 4;
    // split <-> XCD alignment: round-robin dispatch puts wgid%8 on XCD wgid%8,
    // so split = wgid&1 keeps each XCD's L2 on a single 4 MB codebook panel.
    int m0    = (blockIdx.x >> 1) * GBM;
    int cbase = (blockIdx.x & 1) * (CODEBOOK / NS);

    // A fragments resident in VGPRs (all compile-time indexed): 128 VGPR
    v8s aXh[2][8], aXl[2][8];
    #pragma unroll
    for (int mf = 0; mf < 2; mf++) {
        int row = m0 + wm * 32 + mf * 16 + l15;
        #pragma unroll
        for (int ks = 0; ks < 8; ks++) {
            size_t off = (size_t)row * SEM_DIM + ks * 32 + l4 * 8;
            aXh[mf][ks] = *(const v8s*)(Xh + off);
            aXl[mf][ks] = *(const v8s*)(Xl + off);
        }
    }

    v4f acc[2][2];
    #pragma unroll
    for (int mf = 0; mf < 2; mf++)
        #pragma unroll
        for (int nf = 0; nf < 2; nf++)
            acc[mf][nf] = (v4f){0.f, 0.f, 0.f, 0.f};

    float rv[8]; int ri[8];
    #pragma unroll
    for (int s = 0; s < 8; s++) { rv[s] = 3.4e38f; ri[s] = 0; }

    // B fragment loader: fr[0..3] = Eh frags [nf*2+kk], fr[4..7] = El frags.
    // Only addresses depend on runtime nt/sub; fr[] indices are static.
    int nbase = wn * 32 + l15;                // + cbase + nt*64 (+nf*16)
    int kbase = l4 * 8;                       // + sub*64 (+kk*32)
    auto loadB = [&](v8s fr[8], int nt, int sub) {
        int n0 = cbase + nt * 64 + nbase;
        int k0 = sub * 64 + kbase;
        #pragma unroll
        for (int nf = 0; nf < 2; nf++)
            #pragma unroll
            for (int kk = 0; kk < 2; kk++) {
                size_t off = (size_t)(n0 + nf * 16) * SEM_DIM + k0 + kk * 32;
                fr[nf * 2 + kk]     = *(const v8s*)(Eh + off);
                fr[4 + nf * 2 + kk] = *(const v8s*)(El + off);
            }
    };

    auto compute = [&](const v8s fr[8], auto sc) {
        constexpr int SUB = decltype(sc)::v;
        #pragma unroll
        for (int kk = 0; kk < 2; kk++)
            #pragma unroll
            for (int mf = 0; mf < 2; mf++)
                #pragma unroll
                for (int nf = 0; nf < 2; nf++) {
                    acc[mf][nf] = __builtin_amdgcn_mfma_f32_16x16x32_bf16(
                        aXh[mf][SUB * 2 + kk], fr[nf * 2 + kk], acc[mf][nf], 0, 0, 0);
                    acc[mf][nf] = __builtin_amdgcn_mfma_f32_16x16x32_bf16(
                        aXl[mf][SUB * 2 + kk], fr[nf * 2 + kk], acc[mf][nf], 0, 0, 0);
                    acc[mf][nf] = __builtin_amdgcn_mfma_f32_16x16x32_bf16(
                        aXh[mf][SUB * 2 + kk], fr[4 + nf * 2 + kk], acc[mf][nf], 0, 0, 0);
                }
    };

    v8s bA[8], bB[8];
    loadB(bA, 0, 0);

    for (int nt = 0; nt < NTILES; ++nt) {
        loadB(bB, nt, 1);
        compute(bA, IC<0>{});
        loadB(bA, nt, 2);
        compute(bB, IC<1>{});
        loadB(bB, nt, 3);
        compute(bA, IC<2>{});
        if (nt + 1 < NTILES) loadB(bA, nt + 1, 0);
        compute(bB, IC<3>{});

        // epilogue: scores, running-min, threshold emit
        int n0 = cbase + nt * 64;
        int cc0 = n0 + wn * 32 + l15, cc1 = cc0 + 16;
        float e20 = e2[cc0], e21 = e2[cc1];
        #pragma unroll
        for (int mf = 0; mf < 2; mf++)
            #pragma unroll
            for (int r = 0; r < 4; r++) {
                int slot = mf * 4 + r;
                float s0 = fmaf(-2.0f, acc[mf][0][r], e20);
                float s1 = fmaf(-2.0f, acc[mf][1][r], e21);
                float v; int i;
                if (s1 < s0) { v = s1; i = cc1; } else { v = s0; i = cc0; }
                #pragma unroll
                for (int m = 1; m < 16; m <<= 1) {
                    float ov = __shfl_xor(v, m);
                    int   oi = __shfl_xor(i, m);
                    if (ov < v || (ov == v && oi < i)) { v = ov; i = oi; }
                }
                if (v < rv[slot] || (v == rv[slot] && i < ri[slot])) {
                    rv[slot] = v; ri[slot] = i;
                }
                float thr = rv[slot] + DELTA;
                int row = m0 + wm * 32 + mf * 16 + l4 * 4 + r;
                if (s0 <= thr) {
                    int q = atomicAdd(&cnt[row], 1);
                    if (q < cap) cand[(size_t)row * cap + q] = (u16)cc0;
                }
                if (s1 <= thr) {
                    int q = atomicAdd(&cnt[row], 1);
                    if (q < cap) cand[(size_t)row * cap + q] = (u16)cc1;
                }
                acc[mf][0][r] = 0.f;
                acc[mf][1][r] = 0.f;
            }
    }

    // per-row approx-argmin guard (overflow safety)
    #pragma unroll
    for (int slot = 0; slot < 8; slot++) {
        if (l15 == 0) {
            int row = m0 + wm * 32 + (slot >> 2) * 16 + l4 * 4 + (slot & 3);
            u64 key = ((u64)enc_f(rv[slot]) << 32) | (unsigned)ri[slot];
            atomicMin(&amin[row], key);
        }
    }
}

// ---- kernel 4: exact fp32 rescore of candidates, wave-per-row ----
__global__ __launch_bounds__(256) void finalize_kernel(
    const int* __restrict__ cnt, const u16* __restrict__ cand,
    const u64* __restrict__ amin,
    const float* __restrict__ x, const float* __restrict__ es,
    const float* __restrict__ cu, const float* __restrict__ e2,
    float* __restrict__ out, int cap)
{
    int r = (blockIdx.x * 256 + threadIdx.x) >> 6;   // one wave per row
    int lane = threadIdx.x & 63;
    int b = r >> 12, t = r & 4095;

    float xv[4];
    #pragma unroll
    for (int j = 0; j < 4; j++)
        xv[j] = x[((size_t)b * D_ + lane + j * 64) * T_ + t];

    int n = cnt[r]; if (n > cap) n = cap;
    int ai = (int)(unsigned)(amin[r] & 0xFFFFFFFFu);

    float best_s = 3.4e38f; int best_i = 0x7FFFFFFF;
    for (int p = 0; p <= n; p++) {
        int c = (p < n) ? (int)cand[(size_t)r * cap + p] : ai;
        float den = fmaxf(cu[c], EPSV);
        float partial = 0.f;
        #pragma unroll
        for (int j = 0; j < 4; j++)
            partial = fmaf(xv[j], es[(size_t)c * SEM_DIM + lane + j * 64] / den, partial);
        #pragma unroll
        for (int m = 32; m >= 1; m >>= 1) partial += __shfl_xor(partial, m);
        float sc = e2[c] - 2.0f * partial;
        if (sc < best_s || (sc == best_s && c < best_i)) { best_s = sc; best_i = c; }
    }
    if (lane == 0) out[(size_t)b * NCH * T_ + t] = (float)best_i;
}

// ---- kernel 5: FSQ codes + ac recon ----
__global__ __launch_bounds__(256) void fsq_kernel(
    const float* __restrict__ x, float* __restrict__ out)
{
    int e = blockIdx.x * 256 + threadIdx.x;
    int t = e & 4095;
    int rest = e >> 12;
    int j = rest % 36;
    int b = rest / 36;
    float v = x[(size_t)b * D_ * T_ + (size_t)(SEM_DIM + j) * T_ + t];
    float a = tanhf(v);
    float code = rintf((a + 1.0f) * 10.0f);
    out[(size_t)b * NCH * T_ + (size_t)(1 + j) * T_ + t] = code;
    out[RECON_OFF + (size_t)b * D_ * T_ + (size_t)(SEM_DIM + j) * T_ + t]
        = code * 0.1f - 1.0f;
}

// ---- kernel 6: recon sem gather ----
__global__ __launch_bounds__(256) void gather_kernel(
    const float* __restrict__ es, const float* __restrict__ cu,
    const float* __restrict__ codes, float* __restrict__ out)
{
    int bid = blockIdx.x;
    int b  = bid >> 6;
    int tc = bid & 63;
    int t  = tc * 64 + (threadIdx.x & 63);
    int w  = threadIdx.x >> 6;

    int c = (int)codes[(size_t)b * NCH * T_ + t];
    float denom = fmaxf(cu[c], EPSV);
    const float* erow = es + (size_t)c * SEM_DIM;
    float* orow = out + RECON_OFF + (size_t)b * D_ * T_ + t;

    #pragma unroll
    for (int i = 0; i < 16; i++) {
        int d = w * 64 + i * 4;
        float4 ev = *(const float4*)(erow + d);
        orow[(size_t)(d + 0) * T_] = ev.x / denom;
        orow[(size_t)(d + 1) * T_] = ev.y / denom;
        orow[(size_t)(d + 2) * T_] = ev.z / denom;
        orow[(size_t)(d + 3) * T_] = ev.w / denom;
    }
}

extern "C" void kernel_launch(void* const* d_in, const int* in_sizes, int n_in,
                              void* d_out, int out_size, void* d_ws, size_t ws_size,
                              hipStream_t stream)
{
    const float* x  = (const float*)d_in[0];
    const float* es = (const float*)d_in[1];
    const float* cu = (const float*)d_in[2];
    float* out = (float*)d_out;

    u16*   Xh   = (u16*)(out + OFF_XH);
    u16*   Xl   = (u16*)(out + OFF_XL);
    u16*   Eh   = (u16*)(out + OFF_EH);
    u16*   El   = (u16*)(out + OFF_EL);
    float* e2   = out + OFF_E2;
    u64*   amin = (u64*)(out + OFF_AMIN);
    int*   cnt  = (int*)(out + OFF_CNT);

    size_t need = (size_t)ROWS * CAPMAX * sizeof(u16);
    int  cap   = (ws_size >= need) ? CAPMAX : CAPFALL;
    u16* cand  = (ws_size >= need) ? (u16*)d_ws : (u16*)(out + OFF_CAND);

    init_kernel<<<ROWS / 256, 256, 0, stream>>>(amin, cnt);
    prep_emb_kernel<<<CODEBOOK, 256, 0, stream>>>(es, cu, Eh, El, e2);
    prep_x_kernel<<<B_ * 64 * 4, 256, 0, stream>>>(x, Xh, Xl);

    gemm_emit_kernel<<<(ROWS / GBM) * NS, 256, 0, stream>>>(
        Xh, Xl, Eh, El, e2, amin, cnt, cand, cap);

    finalize_kernel<<<ROWS / 4, 256, 0, stream>>>(cnt, cand, amin, x, es, cu, e2, out, cap);

    fsq_kernel<<<(B_ * 36 * T_) / 256, 256, 0, stream>>>(x, out);

    gather_kernel<<<B_ * (T_ / 64), 256, 0, stream>>>(es, cu, out, out);
}

// Round 8
// 586.521 us; speedup vs baseline: 1.9263x; 1.9263x over previous
//
#include <hip/hip_runtime.h>
#include <hip/hip_bf16.h>

// ---- problem constants ----
#define SEM_DIM   256
#define CODEBOOK  8192
#define B_        8
#define T_        4096
#define D_        292
#define NCH       37
#define EPSV      1e-5f
#define NS        2
#define KAPPA     2.05e-3f     // >= 2^-9 deterministic fp16-dot error coeff
#define D0        0.01f        // absolute slack for fp32 epilogue rounding
#define CAP       32

typedef unsigned short u16;
typedef float v4f __attribute__((ext_vector_type(4)));
typedef _Float16 v8h __attribute__((ext_vector_type(8)));

constexpr int ROWS = B_ * T_;                 // 32768
// d_out as flat scratch until final writers run. Scratch spans [0, 5.85M fl);
// finalize/fsq/gather overwrite the full 10.78M-fl output afterwards.
constexpr size_t OFF_XT   = 0;                // fp16[32768*256] = 4,194,304 fl
constexpr size_t OFF_ET   = 4194304;          // fp16[8192*256]  = 1,048,576 fl
constexpr size_t OFF_E2G  = 5242880;          // float2[8192]    = 16,384 fl
constexpr size_t OFF_X2   = 5259264;          // f32[32768]
constexpr size_t OFF_CNT  = 5292032;          // i32[32768]
constexpr size_t OFF_CAND = 5324800;          // u16[32768*32]   = 524,288 fl -> 5,849,088
constexpr size_t RECON_OFF = 1212416;

__device__ __forceinline__ u16 h16bits(float v) {
    _Float16 h = (_Float16)v;
    return *(u16*)&h;
}

// ---- kernel 0: init cnt/x2 ----
__global__ __launch_bounds__(256) void init_kernel(int* __restrict__ cnt,
                                                   float* __restrict__ x2)
{
    int r = blockIdx.x * 256 + threadIdx.x;
    cnt[r] = 0;
    x2[r] = 0.f;
}

// ---- kernel 1: Et = fp16(clamp(es/max(cu,eps))) in panel-transposed layout;
//      e2g = {e2, KAPPA*sqrt(e2)} ----
__global__ __launch_bounds__(256) void prep_emb_kernel(
    const float* __restrict__ es, const float* __restrict__ cu,
    u16* __restrict__ Et, float2* __restrict__ e2g)
{
    int c = blockIdx.x;
    int d = threadIdx.x;
    float denom = fmaxf(cu[c], EPSV);
    float v = es[(size_t)c * SEM_DIM + d] / denom;   // IEEE div, matches ref
    float vc = fminf(fmaxf(v, -60000.f), 60000.f);   // fp16-overflow guard

    __shared__ u16 hbuf[256];
    hbuf[d] = h16bits(vc);

    float s = v * v;
    #pragma unroll
    for (int m = 32; m >= 1; m >>= 1) s += __shfl_xor(s, m);
    __shared__ float red[4];
    int lane = d & 63, w = d >> 6;
    if (lane == 0) red[w] = s;
    __syncthreads();

    if (d < 32) {
        // panel-transposed: byte = (c>>6)*32768 + chunk*1024 + (c&63)*16
        uint4 pk = *(const uint4*)&hbuf[d * 8];
        size_t byt = (size_t)(c >> 6) * 32768 + (size_t)d * 1024 + (size_t)(c & 63) * 16;
        *(uint4*)((char*)Et + byt) = pk;
    }
    if (d == 0) {
        float e2 = red[0] + red[1] + red[2] + red[3];
        e2g[c] = make_float2(e2, KAPPA * sqrtf(e2));
    }
}

// ---- kernel 2: x[:, :256, :] -> Xt (fp16, MFMA-fragment order) + x2 ----
// Xt layout: byte(row,k) = ((R*8+ks)*4+l4)*256 + l15*16, R=row>>4, l15=row&15,
// ks=k>>5, l4=(k>>3)&3, halfs k&7 consecutive.
__global__ __launch_bounds__(256) void prep_x_kernel(
    const float* __restrict__ x, u16* __restrict__ Xt, float* __restrict__ x2)
{
    __shared__ float tile[64][65];
    int bidx = blockIdx.x;            // 8 * 64 * 4
    int dc = bidx & 3;
    int tc = (bidx >> 2) & 63;
    int b  = bidx >> 8;
    int d0 = dc * 64, t0 = tc * 64;
    int tx = threadIdx.x & 63;
    int dq = threadIdx.x >> 6;

    float part = 0.f;
    #pragma unroll
    for (int i = 0; i < 16; i++) {
        int d = dq * 16 + i;
        float v = x[((size_t)b * D_ + d0 + d) * T_ + t0 + tx];
        tile[d][tx] = v;
        part = fmaf(v, v, part);
    }
    atomicAdd(&x2[b * T_ + t0 + tx], part);
    __syncthreads();

    #pragma unroll
    for (int j = 0; j < 2; j++) {
        int lin = threadIdx.x * 2 + j;      // 0..511
        int tr  = lin >> 3;
        int ch  = lin & 7;
        unsigned w[4];
        #pragma unroll
        for (int p = 0; p < 4; p++) {
            float v0 = tile[ch * 8 + p * 2 + 0][tr];
            float v1 = tile[ch * 8 + p * 2 + 1][tr];
            w[p] = (unsigned)h16bits(v0) | ((unsigned)h16bits(v1) << 16);
        }
        int row = b * T_ + t0 + tr;
        int R = row >> 4, l15 = row & 15;
        int k8 = d0 / 8 + ch;
        int ks = k8 >> 2, l4 = k8 & 3;
        size_t byt = (size_t)((R * 8 + ks) * 4 + l4) * 256 + (size_t)l15 * 16;
        *(uint4*)((char*)Xt + byt) = make_uint4(w[0], w[1], w[2], w[3]);
    }
}

// ---- kernel 3: fp16 1-term MFMA GEMM + deterministic-bound emission ----
// 2 waves x m64; B panel (64 codes x 256 K) staged via global_load_lds into
// transposed LDS (conflict-free ds_read_b128); 1 barrier per n-tile.
#define GBM 128
#define NTILES (CODEBOOK / NS / 64)           // 64

__global__ __launch_bounds__(128, 1) void gemm_emit_kernel(
    const u16* __restrict__ Xt, const u16* __restrict__ Et,
    const float2* __restrict__ e2g, const float* __restrict__ x2,
    int* __restrict__ cnt, u16* __restrict__ cand)
{
    __shared__ u16 Bs[2][64 * 256];           // 2 x 32 KB panels
    int tid  = threadIdx.x;
    int lane = tid & 63, wid = tid >> 6;      // 2 waves, m64 each
    int l15 = lane & 15, l4 = lane >> 4;
    int mblk = blockIdx.x >> 1, split = blockIdx.x & 1;   // split <-> XCD parity
    int m0 = mblk * GBM;
    int cbase = split * (CODEBOOK / NS);

    // A resident: 32 v8h = 128 VGPR (all compile-time indexed)
    v8h aX[4][8];
    #pragma unroll
    for (int mf = 0; mf < 4; mf++) {
        int Rb = (m0 + wid * 64 + mf * 16) >> 4;
        #pragma unroll
        for (int ks = 0; ks < 8; ks++) {
            size_t byt = (size_t)((Rb * 8 + ks) * 4 + l4) * 256 + (size_t)l15 * 16;
            aX[mf][ks] = *(const v8h*)((const char*)Xt + byt);
        }
    }

    // per-slot row norms and running min-of-upper-bounds
    float sxv[4][4], rvO[4][4];
    #pragma unroll
    for (int mf = 0; mf < 4; mf++)
        #pragma unroll
        for (int rr = 0; rr < 4; rr++) {
            int row = m0 + wid * 64 + mf * 16 + l4 * 4 + rr;
            sxv[mf][rr] = sqrtf(x2[row]);
            rvO[mf][rr] = 3.4e38f;
        }

    v4f acc[4][4];
    #pragma unroll
    for (int mf = 0; mf < 4; mf++)
        #pragma unroll
        for (int nf = 0; nf < 4; nf++)
            acc[mf][nf] = (v4f){0.f, 0.f, 0.f, 0.f};

    auto stage = [&](int nt, int buf) {
        const char* panel = (const char*)Et + (size_t)(split * 64 + nt) * 32768;
        #pragma unroll
        for (int j = 0; j < 16; j++) {
            int base = (wid * 16 + j) * 1024;
            __builtin_amdgcn_global_load_lds(
                (const __attribute__((address_space(1))) unsigned*)(panel + base + lane * 16),
                (__attribute__((address_space(3))) unsigned*)((char*)&Bs[buf][0] + base),
                16, 0, 0);
        }
    };

    stage(0, 0);

    for (int nt = 0; nt < NTILES; ++nt) {
        int cur = nt & 1;
        __syncthreads();                 // stage(nt) done; buf cur^1 free
        if (nt + 1 < NTILES) stage(nt + 1, cur ^ 1);   // in flight across compute

        #pragma unroll
        for (int ks = 0; ks < 8; ks++) {
            v8h bF[4];
            #pragma unroll
            for (int nf = 0; nf < 4; nf++)
                bF[nf] = *(const v8h*)((const char*)&Bs[cur][0] +
                          (ks * 4 + l4) * 1024 + (nf * 16 + l15) * 16);
            #pragma unroll
            for (int mf = 0; mf < 4; mf++)
                #pragma unroll
                for (int nf = 0; nf < 4; nf++)
                    acc[mf][nf] = __builtin_amdgcn_mfma_f32_16x16x32_f16(
                        aX[mf][ks], bF[nf], acc[mf][nf], 0, 0, 0);
        }

        // epilogue: s = e2 - 2*dot; o = s + sx*g; u = s - sx*g;
        // emit iff u <= min(o) + D0  (deterministic coverage)
        int c0 = cbase + nt * 64;
        float2 eg[4];
        #pragma unroll
        for (int nf = 0; nf < 4; nf++)
            eg[nf] = e2g[c0 + nf * 16 + l15];

        #pragma unroll
        for (int mf = 0; mf < 4; mf++)
            #pragma unroll
            for (int rr = 0; rr < 4; rr++) {
                float sx = sxv[mf][rr];
                float s0 = fmaf(-2.f, acc[mf][0][rr], eg[0].x);
                float s1 = fmaf(-2.f, acc[mf][1][rr], eg[1].x);
                float s2 = fmaf(-2.f, acc[mf][2][rr], eg[2].x);
                float s3 = fmaf(-2.f, acc[mf][3][rr], eg[3].x);
                float o0 = fmaf(sx, eg[0].y, s0), o1 = fmaf(sx, eg[1].y, s1);
                float o2 = fmaf(sx, eg[2].y, s2), o3 = fmaf(sx, eg[3].y, s3);
                float om = fminf(fminf(o0, o1), fminf(o2, o3));
                #pragma unroll
                for (int m = 1; m < 16; m <<= 1)
                    om = fminf(om, __shfl_xor(om, m));
                float rv = fminf(rvO[mf][rr], om);
                rvO[mf][rr] = rv;
                float thr = rv + D0;
                int row = m0 + wid * 64 + mf * 16 + l4 * 4 + rr;
                float u0 = fmaf(-sx, eg[0].y, s0), u1 = fmaf(-sx, eg[1].y, s1);
                float u2 = fmaf(-sx, eg[2].y, s2), u3 = fmaf(-sx, eg[3].y, s3);
                if (u0 <= thr) { int q = atomicAdd(&cnt[row], 1); if (q < CAP) cand[(size_t)row * CAP + q] = (u16)(c0 + 0  + l15); }
                if (u1 <= thr) { int q = atomicAdd(&cnt[row], 1); if (q < CAP) cand[(size_t)row * CAP + q] = (u16)(c0 + 16 + l15); }
                if (u2 <= thr) { int q = atomicAdd(&cnt[row], 1); if (q < CAP) cand[(size_t)row * CAP + q] = (u16)(c0 + 32 + l15); }
                if (u3 <= thr) { int q = atomicAdd(&cnt[row], 1); if (q < CAP) cand[(size_t)row * CAP + q] = (u16)(c0 + 48 + l15); }
                acc[mf][0][rr] = 0.f; acc[mf][1][rr] = 0.f;
                acc[mf][2][rr] = 0.f; acc[mf][3][rr] = 0.f;
            }
    }
}

// ---- kernel 4: exact fp32 rescore, wave-per-row; full-scan on overflow ----
__global__ __launch_bounds__(256) void finalize_kernel(
    const int* __restrict__ cnt, const u16* __restrict__ cand,
    const float* __restrict__ x, const float* __restrict__ es,
    const float* __restrict__ cu, const float2* __restrict__ e2g,
    float* __restrict__ out)
{
    int r = (blockIdx.x * 256 + threadIdx.x) >> 6;   // one wave per row
    int lane = threadIdx.x & 63;
    int b = r >> 12, t = r & 4095;
    int n = cnt[r];

    float best_s = 3.4e38f; int best_i = 0x7FFFFFFF;
    if (n <= CAP) {
        float xv[4];
        #pragma unroll
        for (int j = 0; j < 4; j++)
            xv[j] = x[((size_t)b * D_ + lane + j * 64) * T_ + t];
        for (int p = 0; p < n; p++) {
            int c = (int)cand[(size_t)r * CAP + p];
            float den = fmaxf(cu[c], EPSV);
            float partial = 0.f;
            #pragma unroll
            for (int j = 0; j < 4; j++)
                partial = fmaf(xv[j], es[(size_t)c * SEM_DIM + lane + j * 64] / den, partial);
            #pragma unroll
            for (int m = 32; m >= 1; m >>= 1) partial += __shfl_xor(partial, m);
            float sc = e2g[c].x - 2.0f * partial;
            if (sc < best_s || (sc == best_s && c < best_i)) { best_s = sc; best_i = c; }
        }
    } else {
        // overflow fallback: exact scan of all codes (rare / never in practice)
        for (int c = lane; c < CODEBOOK; c += 64) {
            float den = fmaxf(cu[c], EPSV);
            float acc = 0.f;
            for (int k = 0; k < SEM_DIM; k++) {
                float xv = x[((size_t)b * D_ + k) * T_ + t];
                acc = fmaf(xv, es[(size_t)c * SEM_DIM + k] / den, acc);
            }
            float sc = e2g[c].x - 2.0f * acc;
            if (sc < best_s || (sc == best_s && c < best_i)) { best_s = sc; best_i = c; }
        }
        #pragma unroll
        for (int m = 1; m < 64; m <<= 1) {
            float ov = __shfl_xor(best_s, m);
            int   oi = __shfl_xor(best_i, m);
            if (ov < best_s || (ov == best_s && oi < best_i)) { best_s = ov; best_i = oi; }
        }
    }
    if (lane == 0) out[(size_t)b * NCH * T_ + t] = (float)best_i;
}

// ---- kernel 5: FSQ codes + ac recon ----
__global__ __launch_bounds__(256) void fsq_kernel(
    const float* __restrict__ x, float* __restrict__ out)
{
    int e = blockIdx.x * 256 + threadIdx.x;
    int t = e & 4095;
    int rest = e >> 12;
    int j = rest % 36;
    int b = rest / 36;
    float v = x[(size_t)b * D_ * T_ + (size_t)(SEM_DIM + j) * T_ + t];
    float a = tanhf(v);
    float code = rintf((a + 1.0f) * 10.0f);
    out[(size_t)b * NCH * T_ + (size_t)(1 + j) * T_ + t] = code;
    out[RECON_OFF + (size_t)b * D_ * T_ + (size_t)(SEM_DIM + j) * T_ + t]
        = code * 0.1f - 1.0f;
}

// ---- kernel 6: recon sem gather ----
__global__ __launch_bounds__(256) void gather_kernel(
    const float* __restrict__ es, const float* __restrict__ cu,
    const float* __restrict__ codes, float* __restrict__ out)
{
    int bid = blockIdx.x;
    int b  = bid >> 6;
    int tc = bid & 63;
    int t  = tc * 64 + (threadIdx.x & 63);
    int w  = threadIdx.x >> 6;

    int c = (int)codes[(size_t)b * NCH * T_ + t];
    float denom = fmaxf(cu[c], EPSV);
    const float* erow = es + (size_t)c * SEM_DIM;
    float* orow = out + RECON_OFF + (size_t)b * D_ * T_ + t;

    #pragma unroll
    for (int i = 0; i < 16; i++) {
        int d = w * 64 + i * 4;
        float4 ev = *(const float4*)(erow + d);
        orow[(size_t)(d + 0) * T_] = ev.x / denom;
        orow[(size_t)(d + 1) * T_] = ev.y / denom;
        orow[(size_t)(d + 2) * T_] = ev.z / denom;
        orow[(size_t)(d + 3) * T_] = ev.w / denom;
    }
}

extern "C" void kernel_launch(void* const* d_in, const int* in_sizes, int n_in,
                              void* d_out, int out_size, void* d_ws, size_t ws_size,
                              hipStream_t stream)
{
    const float* x  = (const float*)d_in[0];
    const float* es = (const float*)d_in[1];
    const float* cu = (const float*)d_in[2];
    float* out = (float*)d_out;

    u16*    Xt   = (u16*)(out + OFF_XT);
    u16*    Et   = (u16*)(out + OFF_ET);
    float2* e2g  = (float2*)(out + OFF_E2G);
    float*  x2   = out + OFF_X2;
    int*    cnt  = (int*)(out + OFF_CNT);
    u16*    cand = (u16*)(out + OFF_CAND);

    init_kernel<<<ROWS / 256, 256, 0, stream>>>(cnt, x2);
    prep_emb_kernel<<<CODEBOOK, 256, 0, stream>>>(es, cu, Et, e2g);
    prep_x_kernel<<<B_ * 64 * 4, 256, 0, stream>>>(x, Xt, x2);

    gemm_emit_kernel<<<(ROWS / GBM) * NS, 128, 0, stream>>>(
        Xt, Et, e2g, x2, cnt, cand);

    finalize_kernel<<<ROWS / 4, 256, 0, stream>>>(cnt, cand, x, es, cu, e2g, out);

    fsq_kernel<<<(B_ * 36 * T_) / 256, 256, 0, stream>>>(x, out);

    gather_kernel<<<B_ * (T_ / 64), 256, 0, stream>>>(es, cu, out, out);
}